// Round 2
// baseline (43016.016 us; speedup 1.0000x reference)
//
#include <hip/hip_runtime.h>
#include <cmath>

#define TT 512
#define BB 32
#define HH 1024

// ---------------------------------------------------------------------------
// Fused persistent GRU scan. 256 blocks x 512 threads, 1 block/CU.
// Block owns 4 hidden units j0..j0+3 => 12 rows of W_hh AND 12 rows of W_ih
// stationary in LDS (96 KB). Per step:
//   A) input phase: stage x_t = y_prev[t] (no dependency), 12-row matvec
//   B) poll grid barrier for step t-1
//   C) hidden phase: stage h = y[t-1], 12-row matvec
//   D) gate math on 128 threads, write y[t], accumulate mean-pool
//   E) release-add signal (8 XCD-spread counters)
// Lane tile: 12 rows x 4 batch x 4 k  (1 LDS read : 12 FMA).
// Stage LDS layout: [b][256] fp32, 16B-block index XOR-swizzled by (b&7) so
// stores are contiguous ds_write_b128 and reads are conflict-free b128 (T2).
// ---------------------------------------------------------------------------
__device__ __forceinline__ void mv_phase(
    float (*wAll)[HH],              // [24][1024]; rows [wrow, wrow+12)
    float* stgL,                    // [32*256]
    float (*part)[12][32],          // [16][12][32]
    const float* __restrict__ src,  // [32][1024] row-major
    int wrow, int tid)
{
    const int wv = tid >> 6, l = tid & 63;
    const int ks = l >> 3, bg = l & 7;
    float acc[12][4];
#pragma unroll
    for (int r = 0; r < 12; r++) {
        acc[r][0] = 0.f; acc[r][1] = 0.f; acc[r][2] = 0.f; acc[r][3] = 0.f;
    }

    // prefetch chunk 0 into registers (T14: issue early, write after barrier)
    float4 ld[4];
#pragma unroll
    for (int i = 0; i < 4; i++)
        ld[i] = *(const float4*)&src[(size_t)(i * 8 + wv) * HH + l * 4];

    for (int c = 0; c < 4; c++) {
        __syncthreads();            // stage buffer free (prev consumers done)
#pragma unroll
        for (int i = 0; i < 4; i++) {
            int b = i * 8 + wv;     // wave-uniform row; lanes cover 64 blocks
            *(float4*)&stgL[b * 256 + ((l ^ (b & 7)) << 2)] = ld[i];
        }
        __syncthreads();
        if (c < 3) {
#pragma unroll
            for (int i = 0; i < 4; i++)
                ld[i] = *(const float4*)&src[(size_t)(i * 8 + wv) * HH + (c + 1) * 256 + l * 4];
        }
        const int kw = c * 256 + wv * 32 + ks * 4;   // global k of this lane's 4-k group
        const int kb = wv * 8 + ks;                  // 16B-block index within chunk
        float4 h4[4];
#pragma unroll
        for (int e = 0; e < 4; e++) {
            int b = bg * 4 + e;
            h4[e] = *(const float4*)&stgL[b * 256 + ((kb ^ (b & 7)) << 2)];
        }
#pragma unroll
        for (int r = 0; r < 12; r++) {
            float4 w4 = *(const float4*)&wAll[wrow + r][kw];
#pragma unroll
            for (int e = 0; e < 4; e++) {
                acc[r][e] = fmaf(w4.x, h4[e].x, acc[r][e]);
                acc[r][e] = fmaf(w4.y, h4[e].y, acc[r][e]);
                acc[r][e] = fmaf(w4.z, h4[e].z, acc[r][e]);
                acc[r][e] = fmaf(w4.w, h4[e].w, acc[r][e]);
            }
        }
    }
    // reduce over ks bits 4,5 (2 shfl rounds); remaining split s = ks&1
#pragma unroll
    for (int r = 0; r < 12; r++)
#pragma unroll
        for (int e = 0; e < 4; e++) {
            float v = acc[r][e];
            v += __shfl_xor(v, 16, 64);
            v += __shfl_xor(v, 32, 64);
            acc[r][e] = v;
        }
    if (l < 16) {
        int s = l >> 3, bgw = l & 7;
#pragma unroll
        for (int r = 0; r < 12; r++) {
            float4 o = make_float4(acc[r][0], acc[r][1], acc[r][2], acc[r][3]);
            *(float4*)&part[wv * 2 + s][r][bgw * 4] = o;
        }
    }
}

template<int IN_DIM>
__global__ __launch_bounds__(512, 2) void k_scan(
    const float* __restrict__ xsrc,   // IN_DIM==8: [B][T][8]; else [T][B][H]
    const float* __restrict__ Wih,    // [3H][IN_DIM]
    const float* __restrict__ Whh,    // [3H][H]
    const float* __restrict__ bih,    // [3H]
    const float* __restrict__ bhh,    // [3H]
    float* __restrict__ y,            // [T][B][H]
    int* __restrict__ barx,           // 8 counters, 64B apart
    float* __restrict__ pool)         // null or [B][H]
{
    __shared__ float wAll[24][HH];        // 96 KB: rows 0..11 Whh, 12..23 Wih
    __shared__ float stgL[32 * 256];      // 32 KB staged x_t or h_{t-1}
    __shared__ float part[16][12][32];    // 24.6 KB shared partials
    __shared__ float bi[12], bh[12];
    __shared__ double pool_l[128];

    const int tid = threadIdx.x;
    const int j0 = blockIdx.x * 4;

    // ---- stationary weights ----
    for (int i = tid; i < 12 * 256; i += 512) {
        int r = i >> 8, c4 = (i & 255) * 4;
        int g = r >> 2, jj = r & 3;
        float4 v = *(const float4*)&Whh[(size_t)(g * HH + j0 + jj) * HH + c4];
        wAll[r][c4 + 0] = v.x; wAll[r][c4 + 1] = v.y;
        wAll[r][c4 + 2] = v.z; wAll[r][c4 + 3] = v.w;
    }
    if (IN_DIM == HH) {
        for (int i = tid; i < 12 * 256; i += 512) {
            int r = i >> 8, c4 = (i & 255) * 4;
            int g = r >> 2, jj = r & 3;
            float4 v = *(const float4*)&Wih[(size_t)(g * HH + j0 + jj) * HH + c4];
            wAll[12 + r][c4 + 0] = v.x; wAll[12 + r][c4 + 1] = v.y;
            wAll[12 + r][c4 + 2] = v.z; wAll[12 + r][c4 + 3] = v.w;
        }
    } else {
        if (tid < 96) {
            int r = tid >> 3, d = tid & 7;
            int g = r >> 2, jj = r & 3;
            wAll[12 + r][d] = Wih[(size_t)(g * HH + j0 + jj) * IN_DIM + d];
        }
    }
    if (tid < 12) {
        int g = tid >> 2, jj = tid & 3;
        bi[tid] = bih[g * HH + j0 + jj];
        bh[tid] = bhh[g * HH + j0 + jj];
    }
    if (tid < 128) pool_l[tid] = 0.0;
    __syncthreads();

    for (int t = 0; t < TT; t++) {
        double ig0 = 0.0, ig1 = 0.0, ig2 = 0.0;
        // ---- A: input phase (no cross-block dependency; hides barrier) ----
        if (IN_DIM == HH) {
            mv_phase(wAll, stgL, part, xsrc + (size_t)t * BB * HH, 12, tid);
            __syncthreads();
            if (tid < 128) {
                int b = tid >> 2, jj = tid & 3;
                ig0 = bi[jj]; ig1 = bi[4 + jj]; ig2 = bi[8 + jj];
#pragma unroll
                for (int p = 0; p < 16; p++) {
                    ig0 += part[p][jj][b];
                    ig1 += part[p][4 + jj][b];
                    ig2 += part[p][8 + jj][b];
                }
            }
        }
        // ---- B: grid barrier for step t-1 ----
        if (t > 0) {
            if (tid < 8) {
                const int target = 32 * t;
                while (__hip_atomic_load(&barx[tid * 16], __ATOMIC_RELAXED,
                                         __HIP_MEMORY_SCOPE_AGENT) < target)
                    __builtin_amdgcn_s_sleep(2);
            }
            __syncthreads();
            // ---- C: hidden phase ----
            mv_phase(wAll, stgL, part, y + (size_t)(t - 1) * BB * HH, 0, tid);
            __syncthreads();
        }
        // ---- D: gates ----
        if (tid < 128) {
            int b = tid >> 2, jj = tid & 3, jg = j0 + jj;
            double hg0 = bh[jj], hg1 = bh[4 + jj], hg2 = bh[8 + jj];
            float hp = 0.f;
            if (t > 0) {
#pragma unroll
                for (int p = 0; p < 16; p++) {
                    hg0 += part[p][jj][b];
                    hg1 += part[p][4 + jj][b];
                    hg2 += part[p][8 + jj][b];
                }
                hp = y[(size_t)(t - 1) * BB * HH + b * HH + jg];
            }
            if (IN_DIM != HH) {
                const float* xp = xsrc + ((size_t)b * TT + t) * IN_DIM;
                float xv[8];
                *(float4*)&xv[0] = *(const float4*)&xp[0];
                *(float4*)&xv[4] = *(const float4*)&xp[4];
                float s0 = 0.f, s1 = 0.f, s2 = 0.f;
#pragma unroll
                for (int d = 0; d < 8; d++) {
                    s0 = fmaf(wAll[12 + jj][d], xv[d], s0);
                    s1 = fmaf(wAll[16 + jj][d], xv[d], s1);
                    s2 = fmaf(wAll[20 + jj][d], xv[d], s2);
                }
                ig0 = (double)bi[jj] + s0;
                ig1 = (double)bi[4 + jj] + s1;
                ig2 = (double)bi[8 + jj] + s2;
            }
            float rr = 1.f / (1.f + expf(-(float)(ig0 + hg0)));
            float zz = 1.f / (1.f + expf(-(float)(ig1 + hg1)));
            float nn = tanhf((float)(ig2 + (double)rr * hg2));
            float hnew = (1.f - zz) * nn + zz * hp;
            y[(size_t)t * BB * HH + b * HH + jg] = hnew;
            if (pool != nullptr) pool_l[tid] += (double)hnew;
        }
        // ---- E: signal ----
        if (t < TT - 1) {
            __syncthreads();   // drains all waves' y[t] stores (vmcnt0 before barrier)
            if (tid == 0)
                __hip_atomic_fetch_add(&barx[(blockIdx.x & 7) * 16], 1,
                                       __ATOMIC_RELEASE, __HIP_MEMORY_SCOPE_AGENT);
        }
    }
    __syncthreads();
    if (pool != nullptr && tid < 128) {
        int b = tid >> 2, jj = tid & 3;
        pool[b * HH + j0 + jj] = (float)(pool_l[tid] * (1.0 / 512.0));
    }
}

// ---------------------------------------------------------------------------
// FC head: out[b][o] = (relu)(sum_k in[b][k]*w[o][k] + bias[o]), double accum
// ---------------------------------------------------------------------------
__global__ __launch_bounds__(256) void k_fc(const float* __restrict__ in,
                                            const float* __restrict__ w,
                                            const float* __restrict__ bias,
                                            float* __restrict__ out,
                                            int ind, int outd, int dorelu)
{
    int b = blockIdx.y;
    int o = blockIdx.x * 256 + threadIdx.x;
    if (o >= outd) return;
    const float* ip = in + (size_t)b * ind;
    const float* wp = w + (size_t)o * ind;
    double s = (double)bias[o];
    for (int k = 0; k < ind; k += 4) {
        float4 wv = *(const float4*)&wp[k];
        float4 iv = *(const float4*)&ip[k];
        s += (double)iv.x * wv.x + (double)iv.y * wv.y
           + (double)iv.z * wv.z + (double)iv.w * wv.w;
    }
    float v = (float)s;
    if (dorelu) v = fmaxf(v, 0.f);
    out[(size_t)b * outd + o] = v;
}

// ---------------------------------------------------------------------------
extern "C" void kernel_launch(void* const* d_in, const int* in_sizes, int n_in,
                              void* d_out, int out_size, void* d_ws, size_t ws_size,
                              hipStream_t stream)
{
    (void)in_sizes; (void)n_in; (void)out_size;
    const float* x    = (const float*)d_in[0];
    const float* Wih0 = (const float*)d_in[1];
    const float* Whh0 = (const float*)d_in[2];
    const float* bih0 = (const float*)d_in[3];
    const float* bhh0 = (const float*)d_in[4];
    const float* Wih1 = (const float*)d_in[5];
    const float* Whh1 = (const float*)d_in[6];
    const float* bih1 = (const float*)d_in[7];
    const float* bhh1 = (const float*)d_in[8];
    const float* Wih2 = (const float*)d_in[9];
    const float* Whh2 = (const float*)d_in[10];
    const float* bih2 = (const float*)d_in[11];
    const float* bhh2 = (const float*)d_in[12];
    const float* fc1w = (const float*)d_in[13];
    const float* fc1b = (const float*)d_in[14];
    const float* fc2w = (const float*)d_in[15];
    const float* fc2b = (const float*)d_in[16];
    const float* fc3w = (const float*)d_in[17];
    const float* fc3b = (const float*)d_in[18];

    // workspace layout (total 134.45 MB)
    int*   bars   = (int*)d_ws;                       // 3 x 8 counters x 16-int pad
    float* pooled = (float*)d_ws + 512;               // [32][1024]
    float* fc1o   = pooled + 32 * 1024;               // [32][512]
    float* fc2o   = fc1o + 32 * 512;                  // [32][256]
    float* y0     = fc2o + 32 * 256;                  // [512][32][1024] = 67.1 MB
    float* y1     = y0 + (size_t)TT * BB * HH;        // 67.1 MB

    const size_t need = (size_t)(512 + 32 * 1024 + 32 * 512 + 32 * 256) * 4
                      + 2ull * TT * BB * HH * 4;
    if (ws_size < need) return;  // diagnostic: clean absmax fail => ws too small

    hipMemsetAsync(bars, 0, 3 * 128 * sizeof(int), stream);

    // layer 0 (IN=8), layer 1, layer 2 (fused mean-pool; reuses y0)
    k_scan<8>   <<<256, 512, 0, stream>>>(x,  Wih0, Whh0, bih0, bhh0, y0, bars,       nullptr);
    k_scan<HH>  <<<256, 512, 0, stream>>>(y0, Wih1, Whh1, bih1, bhh1, y1, bars + 128, nullptr);
    k_scan<HH>  <<<256, 512, 0, stream>>>(y1, Wih2, Whh2, bih2, bhh2, y0, bars + 256, pooled);

    // head
    k_fc<<<dim3(2, 32), 256, 0, stream>>>(pooled, fc1w, fc1b, fc1o, HH, 512, 1);
    k_fc<<<dim3(1, 32), 256, 0, stream>>>(fc1o, fc2w, fc2b, fc2o, 512, 256, 1);
    k_fc<<<dim3(1, 32), 256, 0, stream>>>(fc2o, fc3w, fc3b, (float*)d_out, 256, 1, 0);
}

// Round 3
// 33501.666 us; speedup vs baseline: 1.2840x; 1.2840x over previous
//
#include <hip/hip_runtime.h>
#include <cmath>

#define TT 512
#define BB 32
#define HH 1024

// ---------------------------------------------------------------------------
// Fused persistent GRU scan. 256 blocks x 512 threads, 1 block/CU.
// Block owns 4 hidden units j0..j0+3 => 12 rows of W_hh AND 12 rows of W_ih
// stationary in LDS (96 KB). Per step:
//   A) input phase: stage x_t = y_prev[t] (no dependency), 12-row matvec
//   B) poll grid barrier for step t-1
//   C) hidden phase: stage h = y[t-1], 12-row matvec
//   D) gate math on 128 threads, write y[t] (agent-relaxed atomic stores ->
//      visible at device coherence point, NO L2 writeback needed)
//   E) relaxed signal add (ordering via __syncthreads vmcnt(0) drain)
// Lane tile: 12 rows x 4 batch x 4 k  (1 LDS read : 12 FMA).
// Stage LDS layout: [b][256] fp32, 16B-block index XOR-swizzled by (b&7) so
// stores are contiguous ds_write_b128 and reads are conflict-free b128 (T2).
// ---------------------------------------------------------------------------
__device__ __forceinline__ void mv_phase(
    float (*wAll)[HH],              // [24][1024]; rows [wrow, wrow+12)
    float* stgL,                    // [32*256]
    float (*part)[12][32],          // [16][12][32]
    const float* __restrict__ src,  // [32][1024] row-major
    int wrow, int tid)
{
    const int wv = tid >> 6, l = tid & 63;
    const int ks = l >> 3, bg = l & 7;
    float acc[12][4];
#pragma unroll
    for (int r = 0; r < 12; r++) {
        acc[r][0] = 0.f; acc[r][1] = 0.f; acc[r][2] = 0.f; acc[r][3] = 0.f;
    }

    // prefetch chunk 0 into registers (T14: issue early, write after barrier)
    float4 ld[4];
#pragma unroll
    for (int i = 0; i < 4; i++)
        ld[i] = *(const float4*)&src[(size_t)(i * 8 + wv) * HH + l * 4];

    for (int c = 0; c < 4; c++) {
        __syncthreads();            // stage buffer free (prev consumers done)
#pragma unroll
        for (int i = 0; i < 4; i++) {
            int b = i * 8 + wv;     // wave-uniform row; lanes cover 64 blocks
            *(float4*)&stgL[b * 256 + ((l ^ (b & 7)) << 2)] = ld[i];
        }
        __syncthreads();
        if (c < 3) {
#pragma unroll
            for (int i = 0; i < 4; i++)
                ld[i] = *(const float4*)&src[(size_t)(i * 8 + wv) * HH + (c + 1) * 256 + l * 4];
        }
        const int kw = c * 256 + wv * 32 + ks * 4;   // global k of this lane's 4-k group
        const int kb = wv * 8 + ks;                  // 16B-block index within chunk
        float4 h4[4];
#pragma unroll
        for (int e = 0; e < 4; e++) {
            int b = bg * 4 + e;
            h4[e] = *(const float4*)&stgL[b * 256 + ((kb ^ (b & 7)) << 2)];
        }
#pragma unroll
        for (int r = 0; r < 12; r++) {
            float4 w4 = *(const float4*)&wAll[wrow + r][kw];
#pragma unroll
            for (int e = 0; e < 4; e++) {
                acc[r][e] = fmaf(w4.x, h4[e].x, acc[r][e]);
                acc[r][e] = fmaf(w4.y, h4[e].y, acc[r][e]);
                acc[r][e] = fmaf(w4.z, h4[e].z, acc[r][e]);
                acc[r][e] = fmaf(w4.w, h4[e].w, acc[r][e]);
            }
        }
    }
    // reduce over ks bits 4,5 (2 shfl rounds); remaining split s = ks&1
#pragma unroll
    for (int r = 0; r < 12; r++)
#pragma unroll
        for (int e = 0; e < 4; e++) {
            float v = acc[r][e];
            v += __shfl_xor(v, 16, 64);
            v += __shfl_xor(v, 32, 64);
            acc[r][e] = v;
        }
    if (l < 16) {
        int s = l >> 3, bgw = l & 7;
#pragma unroll
        for (int r = 0; r < 12; r++) {
            float4 o = make_float4(acc[r][0], acc[r][1], acc[r][2], acc[r][3]);
            *(float4*)&part[wv * 2 + s][r][bgw * 4] = o;
        }
    }
}

template<int IN_DIM>
__global__ __launch_bounds__(512, 2) void k_scan(
    const float* __restrict__ xsrc,   // IN_DIM==8: [B][T][8]; else [T][B][H]
    const float* __restrict__ Wih,    // [3H][IN_DIM]
    const float* __restrict__ Whh,    // [3H][H]
    const float* __restrict__ bih,    // [3H]
    const float* __restrict__ bhh,    // [3H]
    float* __restrict__ y,            // [T][B][H]
    int* __restrict__ barx,           // 8 counters, 64B apart
    float* __restrict__ pool)         // null or [B][H]
{
    __shared__ float wAll[24][HH];        // 96 KB: rows 0..11 Whh, 12..23 Wih
    __shared__ float stgL[32 * 256];      // 32 KB staged x_t or h_{t-1}
    __shared__ float part[16][12][32];    // 24.6 KB shared partials
    __shared__ float bi[12], bh[12];
    __shared__ double pool_l[128];

    const int tid = threadIdx.x;
    const int j0 = blockIdx.x * 4;

    // ---- stationary weights ----
    for (int i = tid; i < 12 * 256; i += 512) {
        int r = i >> 8, c4 = (i & 255) * 4;
        int g = r >> 2, jj = r & 3;
        float4 v = *(const float4*)&Whh[(size_t)(g * HH + j0 + jj) * HH + c4];
        wAll[r][c4 + 0] = v.x; wAll[r][c4 + 1] = v.y;
        wAll[r][c4 + 2] = v.z; wAll[r][c4 + 3] = v.w;
    }
    if (IN_DIM == HH) {
        for (int i = tid; i < 12 * 256; i += 512) {
            int r = i >> 8, c4 = (i & 255) * 4;
            int g = r >> 2, jj = r & 3;
            float4 v = *(const float4*)&Wih[(size_t)(g * HH + j0 + jj) * HH + c4];
            wAll[12 + r][c4 + 0] = v.x; wAll[12 + r][c4 + 1] = v.y;
            wAll[12 + r][c4 + 2] = v.z; wAll[12 + r][c4 + 3] = v.w;
        }
    } else {
        if (tid < 96) {
            int r = tid >> 3, d = tid & 7;
            int g = r >> 2, jj = r & 3;
            wAll[12 + r][d] = Wih[(size_t)(g * HH + j0 + jj) * IN_DIM + d];
        }
    }
    if (tid < 12) {
        int g = tid >> 2, jj = tid & 3;
        bi[tid] = bih[g * HH + j0 + jj];
        bh[tid] = bhh[g * HH + j0 + jj];
    }
    if (tid < 128) pool_l[tid] = 0.0;
    __syncthreads();

    for (int t = 0; t < TT; t++) {
        double ig0 = 0.0, ig1 = 0.0, ig2 = 0.0;
        // ---- A: input phase (no cross-block dependency; hides barrier) ----
        if (IN_DIM == HH) {
            mv_phase(wAll, stgL, part, xsrc + (size_t)t * BB * HH, 12, tid);
            __syncthreads();
            if (tid < 128) {
                int b = tid >> 2, jj = tid & 3;
                ig0 = bi[jj]; ig1 = bi[4 + jj]; ig2 = bi[8 + jj];
#pragma unroll
                for (int p = 0; p < 16; p++) {
                    ig0 += part[p][jj][b];
                    ig1 += part[p][4 + jj][b];
                    ig2 += part[p][8 + jj][b];
                }
            }
        }
        // ---- B: grid barrier for step t-1 ----
        if (t > 0) {
            if (tid < 8) {
                const int target = 32 * t;
                while (__hip_atomic_load(&barx[tid * 16], __ATOMIC_RELAXED,
                                         __HIP_MEMORY_SCOPE_AGENT) < target)
                    __builtin_amdgcn_s_sleep(2);
            }
            __syncthreads();
            // ---- C: hidden phase ----
            mv_phase(wAll, stgL, part, y + (size_t)(t - 1) * BB * HH, 0, tid);
            __syncthreads();
        }
        // ---- D: gates ----
        if (tid < 128) {
            int b = tid >> 2, jj = tid & 3, jg = j0 + jj;
            double hg0 = bh[jj], hg1 = bh[4 + jj], hg2 = bh[8 + jj];
            float hp = 0.f;
            if (t > 0) {
#pragma unroll
                for (int p = 0; p < 16; p++) {
                    hg0 += part[p][jj][b];
                    hg1 += part[p][4 + jj][b];
                    hg2 += part[p][8 + jj][b];
                }
                hp = y[(size_t)(t - 1) * BB * HH + b * HH + jg];
            }
            if (IN_DIM != HH) {
                const float* xp = xsrc + ((size_t)b * TT + t) * IN_DIM;
                float xv[8];
                *(float4*)&xv[0] = *(const float4*)&xp[0];
                *(float4*)&xv[4] = *(const float4*)&xp[4];
                float s0 = 0.f, s1 = 0.f, s2 = 0.f;
#pragma unroll
                for (int d = 0; d < 8; d++) {
                    s0 = fmaf(wAll[12 + jj][d], xv[d], s0);
                    s1 = fmaf(wAll[16 + jj][d], xv[d], s1);
                    s2 = fmaf(wAll[20 + jj][d], xv[d], s2);
                }
                ig0 = (double)bi[jj] + s0;
                ig1 = (double)bi[4 + jj] + s1;
                ig2 = (double)bi[8 + jj] + s2;
            }
            float rr = 1.f / (1.f + expf(-(float)(ig0 + hg0)));
            float zz = 1.f / (1.f + expf(-(float)(ig1 + hg1)));
            float nn = tanhf((float)(ig2 + (double)rr * hg2));
            float hnew = (1.f - zz) * nn + zz * hp;
            // agent-scope relaxed atomic store: visible at device coherence
            // point without any L2 writeback fence
            __hip_atomic_store(&y[(size_t)t * BB * HH + b * HH + jg], hnew,
                               __ATOMIC_RELAXED, __HIP_MEMORY_SCOPE_AGENT);
            if (pool != nullptr) pool_l[tid] += (double)hnew;
        }
        // ---- E: signal (relaxed; __syncthreads already drained vmcnt) ----
        if (t < TT - 1) {
            __syncthreads();   // all waves' y[t] stores acked before signal
            if (tid == 0)
                __hip_atomic_fetch_add(&barx[(blockIdx.x & 7) * 16], 1,
                                       __ATOMIC_RELAXED, __HIP_MEMORY_SCOPE_AGENT);
        }
    }
    __syncthreads();
    if (pool != nullptr && tid < 128) {
        int b = tid >> 2, jj = tid & 3;
        pool[b * HH + j0 + jj] = (float)(pool_l[tid] * (1.0 / 512.0));
    }
}

// ---------------------------------------------------------------------------
// FC head: out[b][o] = (relu)(sum_k in[b][k]*w[o][k] + bias[o]), double accum
// ---------------------------------------------------------------------------
__global__ __launch_bounds__(256) void k_fc(const float* __restrict__ in,
                                            const float* __restrict__ w,
                                            const float* __restrict__ bias,
                                            float* __restrict__ out,
                                            int ind, int outd, int dorelu)
{
    int b = blockIdx.y;
    int o = blockIdx.x * 256 + threadIdx.x;
    if (o >= outd) return;
    const float* ip = in + (size_t)b * ind;
    const float* wp = w + (size_t)o * ind;
    double s = (double)bias[o];
    for (int k = 0; k < ind; k += 4) {
        float4 wv = *(const float4*)&wp[k];
        float4 iv = *(const float4*)&ip[k];
        s += (double)iv.x * wv.x + (double)iv.y * wv.y
           + (double)iv.z * wv.z + (double)iv.w * wv.w;
    }
    float v = (float)s;
    if (dorelu) v = fmaxf(v, 0.f);
    out[(size_t)b * outd + o] = v;
}

// ---------------------------------------------------------------------------
extern "C" void kernel_launch(void* const* d_in, const int* in_sizes, int n_in,
                              void* d_out, int out_size, void* d_ws, size_t ws_size,
                              hipStream_t stream)
{
    (void)in_sizes; (void)n_in; (void)out_size;
    const float* x    = (const float*)d_in[0];
    const float* Wih0 = (const float*)d_in[1];
    const float* Whh0 = (const float*)d_in[2];
    const float* bih0 = (const float*)d_in[3];
    const float* bhh0 = (const float*)d_in[4];
    const float* Wih1 = (const float*)d_in[5];
    const float* Whh1 = (const float*)d_in[6];
    const float* bih1 = (const float*)d_in[7];
    const float* bhh1 = (const float*)d_in[8];
    const float* Wih2 = (const float*)d_in[9];
    const float* Whh2 = (const float*)d_in[10];
    const float* bih2 = (const float*)d_in[11];
    const float* bhh2 = (const float*)d_in[12];
    const float* fc1w = (const float*)d_in[13];
    const float* fc1b = (const float*)d_in[14];
    const float* fc2w = (const float*)d_in[15];
    const float* fc2b = (const float*)d_in[16];
    const float* fc3w = (const float*)d_in[17];
    const float* fc3b = (const float*)d_in[18];

    // workspace layout (total 134.45 MB)
    int*   bars   = (int*)d_ws;                       // 3 x 8 counters x 16-int pad
    float* pooled = (float*)d_ws + 512;               // [32][1024]
    float* fc1o   = pooled + 32 * 1024;               // [32][512]
    float* fc2o   = fc1o + 32 * 512;                  // [32][256]
    float* y0     = fc2o + 32 * 256;                  // [512][32][1024] = 67.1 MB
    float* y1     = y0 + (size_t)TT * BB * HH;        // 67.1 MB

    const size_t need = (size_t)(512 + 32 * 1024 + 32 * 512 + 32 * 256) * 4
                      + 2ull * TT * BB * HH * 4;
    if (ws_size < need) return;  // diagnostic: clean absmax fail => ws too small

    hipMemsetAsync(bars, 0, 3 * 128 * sizeof(int), stream);

    // layer 0 (IN=8), layer 1, layer 2 (fused mean-pool; reuses y0)
    k_scan<8>   <<<256, 512, 0, stream>>>(x,  Wih0, Whh0, bih0, bhh0, y0, bars,       nullptr);
    k_scan<HH>  <<<256, 512, 0, stream>>>(y0, Wih1, Whh1, bih1, bhh1, y1, bars + 128, nullptr);
    k_scan<HH>  <<<256, 512, 0, stream>>>(y1, Wih2, Whh2, bih2, bhh2, y0, bars + 256, pooled);

    // head
    k_fc<<<dim3(2, 32), 256, 0, stream>>>(pooled, fc1w, fc1b, fc1o, HH, 512, 1);
    k_fc<<<dim3(1, 32), 256, 0, stream>>>(fc1o, fc2w, fc2b, fc2o, 512, 256, 1);
    k_fc<<<dim3(1, 32), 256, 0, stream>>>(fc2o, fc3w, fc3b, (float*)d_out, 256, 1, 0);
}

// Round 5
// 33408.929 us; speedup vs baseline: 1.2876x; 1.0028x over previous
//
#include <hip/hip_runtime.h>
#include <cmath>

#define TT 512
#define BB 32
#define HH 1024
#define G3 3072

// ---------------------------------------------------------------------------
// Shared matvec phase for the persistent scans. Lane tile: 12r x 4b x 4k.
// Stage LDS layout: [b][256] fp32, 16B-block index XOR-swizzled by (b&7).
// ---------------------------------------------------------------------------
__device__ __forceinline__ void mv_phase(
    float (*wAll)[HH],              // rows [wrow, wrow+12)
    float* stgL,                    // [32*256]
    float (*part)[12][32],          // [16][12][32]
    const float* __restrict__ src,  // [32][1024] row-major
    int wrow, int tid)
{
    const int wv = tid >> 6, l = tid & 63;
    const int ks = l >> 3, bg = l & 7;
    float acc[12][4];
#pragma unroll
    for (int r = 0; r < 12; r++) {
        acc[r][0] = 0.f; acc[r][1] = 0.f; acc[r][2] = 0.f; acc[r][3] = 0.f;
    }

    float4 ld[4];
#pragma unroll
    for (int i = 0; i < 4; i++)
        ld[i] = *(const float4*)&src[(size_t)(i * 8 + wv) * HH + l * 4];

    for (int c = 0; c < 4; c++) {
        __syncthreads();
#pragma unroll
        for (int i = 0; i < 4; i++) {
            int b = i * 8 + wv;
            *(float4*)&stgL[b * 256 + ((l ^ (b & 7)) << 2)] = ld[i];
        }
        __syncthreads();
        if (c < 3) {
#pragma unroll
            for (int i = 0; i < 4; i++)
                ld[i] = *(const float4*)&src[(size_t)(i * 8 + wv) * HH + (c + 1) * 256 + l * 4];
        }
        const int kw = c * 256 + wv * 32 + ks * 4;
        const int kb = wv * 8 + ks;
        float4 h4[4];
#pragma unroll
        for (int e = 0; e < 4; e++) {
            int b = bg * 4 + e;
            h4[e] = *(const float4*)&stgL[b * 256 + ((kb ^ (b & 7)) << 2)];
        }
#pragma unroll
        for (int r = 0; r < 12; r++) {
            float4 w4 = *(const float4*)&wAll[wrow + r][kw];
#pragma unroll
            for (int e = 0; e < 4; e++) {
                acc[r][e] = fmaf(w4.x, h4[e].x, acc[r][e]);
                acc[r][e] = fmaf(w4.y, h4[e].y, acc[r][e]);
                acc[r][e] = fmaf(w4.z, h4[e].z, acc[r][e]);
                acc[r][e] = fmaf(w4.w, h4[e].w, acc[r][e]);
            }
        }
    }
#pragma unroll
    for (int r = 0; r < 12; r++)
#pragma unroll
        for (int e = 0; e < 4; e++) {
            float v = acc[r][e];
            v += __shfl_xor(v, 16, 64);
            v += __shfl_xor(v, 32, 64);
            acc[r][e] = v;
        }
    if (l < 16) {
        int s = l >> 3, bgw = l & 7;
#pragma unroll
        for (int r = 0; r < 12; r++) {
            float4 o = make_float4(acc[r][0], acc[r][1], acc[r][2], acc[r][3]);
            *(float4*)&part[wv * 2 + s][r][bgw * 4] = o;
        }
    }
}

// ---------------------------------------------------------------------------
// Fallback / layer-0 scan (round-3 structure + register-carried h_prev).
// ---------------------------------------------------------------------------
template<int IN_DIM>
__global__ __launch_bounds__(512, 2) void k_scan(
    const float* __restrict__ xsrc,   // IN_DIM==8: [B][T][8]; else [T][B][H]
    const float* __restrict__ Wih,
    const float* __restrict__ Whh,
    const float* __restrict__ bih,
    const float* __restrict__ bhh,
    float* __restrict__ y,
    int* __restrict__ barx,
    float* __restrict__ pool)
{
    __shared__ float wAll[24][HH];
    __shared__ float stgL[32 * 256];
    __shared__ float part[16][12][32];
    __shared__ float bi[12], bh[12];
    __shared__ double pool_l[128];

    const int tid = threadIdx.x;
    const int j0 = blockIdx.x * 4;

    for (int i = tid; i < 12 * 256; i += 512) {
        int r = i >> 8, c4 = (i & 255) * 4;
        int g = r >> 2, jj = r & 3;
        *(float4*)&wAll[r][c4] =
            *(const float4*)&Whh[(size_t)(g * HH + j0 + jj) * HH + c4];
    }
    if (IN_DIM == HH) {
        for (int i = tid; i < 12 * 256; i += 512) {
            int r = i >> 8, c4 = (i & 255) * 4;
            int g = r >> 2, jj = r & 3;
            *(float4*)&wAll[12 + r][c4] =
                *(const float4*)&Wih[(size_t)(g * HH + j0 + jj) * HH + c4];
        }
    } else {
        if (tid < 96) {
            int r = tid >> 3, d = tid & 7;
            int g = r >> 2, jj = r & 3;
            wAll[12 + r][d] = Wih[(size_t)(g * HH + j0 + jj) * IN_DIM + d];
        }
    }
    if (tid < 12) {
        int g = tid >> 2, jj = tid & 3;
        bi[tid] = bih[g * HH + j0 + jj];
        bh[tid] = bhh[g * HH + j0 + jj];
    }
    if (tid < 128) pool_l[tid] = 0.0;
    __syncthreads();

    float hp_reg = 0.f;   // this thread's own h_prev (gate thread (b,jj))
    for (int t = 0; t < TT; t++) {
        double ig0 = 0.0, ig1 = 0.0, ig2 = 0.0;
        if (IN_DIM == HH) {
            mv_phase(wAll, stgL, part, xsrc + (size_t)t * BB * HH, 12, tid);
            __syncthreads();
            if (tid < 128) {
                int b = tid >> 2, jj = tid & 3;
                ig0 = bi[jj]; ig1 = bi[4 + jj]; ig2 = bi[8 + jj];
#pragma unroll
                for (int p = 0; p < 16; p++) {
                    ig0 += part[p][jj][b];
                    ig1 += part[p][4 + jj][b];
                    ig2 += part[p][8 + jj][b];
                }
            }
        }
        if (t > 0) {
            if (tid < 8) {
                const int target = 32 * t;
                while (__hip_atomic_load(&barx[tid * 16], __ATOMIC_RELAXED,
                                         __HIP_MEMORY_SCOPE_AGENT) < target)
                    __builtin_amdgcn_s_sleep(2);
            }
            __syncthreads();
            mv_phase(wAll, stgL, part, y + (size_t)(t - 1) * BB * HH, 0, tid);
            __syncthreads();
        }
        if (tid < 128) {
            int b = tid >> 2, jj = tid & 3, jg = j0 + jj;
            double hg0 = bh[jj], hg1 = bh[4 + jj], hg2 = bh[8 + jj];
            if (t > 0) {
#pragma unroll
                for (int p = 0; p < 16; p++) {
                    hg0 += part[p][jj][b];
                    hg1 += part[p][4 + jj][b];
                    hg2 += part[p][8 + jj][b];
                }
            }
            if (IN_DIM != HH) {
                const float* xp = xsrc + ((size_t)b * TT + t) * IN_DIM;
                float xv[8];
                *(float4*)&xv[0] = *(const float4*)&xp[0];
                *(float4*)&xv[4] = *(const float4*)&xp[4];
                float s0 = 0.f, s1 = 0.f, s2 = 0.f;
#pragma unroll
                for (int d = 0; d < 8; d++) {
                    s0 = fmaf(wAll[12 + jj][d], xv[d], s0);
                    s1 = fmaf(wAll[16 + jj][d], xv[d], s1);
                    s2 = fmaf(wAll[20 + jj][d], xv[d], s2);
                }
                ig0 = (double)bi[jj] + s0;
                ig1 = (double)bi[4 + jj] + s1;
                ig2 = (double)bi[8 + jj] + s2;
            }
            float rr = 1.f / (1.f + expf(-(float)(ig0 + hg0)));
            float zz = 1.f / (1.f + expf(-(float)(ig1 + hg1)));
            float nn = tanhf((float)(ig2 + (double)rr * hg2));
            float hnew = (1.f - zz) * nn + zz * hp_reg;
            hp_reg = hnew;
            __hip_atomic_store(&y[(size_t)t * BB * HH + b * HH + jg], hnew,
                               __ATOMIC_RELAXED, __HIP_MEMORY_SCOPE_AGENT);
            if (pool != nullptr) pool_l[tid] += (double)hnew;
        }
        if (t < TT - 1) {
            __syncthreads();
            if (tid == 0)
                __hip_atomic_fetch_add(&barx[(blockIdx.x & 7) * 16], 1,
                                       __ATOMIC_RELAXED, __HIP_MEMORY_SCOPE_AGENT);
        }
    }
    __syncthreads();
    if (pool != nullptr && tid < 128) {
        int b = tid >> 2, jj = tid & 3;
        pool[b * HH + j0 + jj] = (float)(pool_l[tid] * (1.0 / 512.0));
    }
}

// ---------------------------------------------------------------------------
// Hidden-only scan: input gates precomputed into xg[(t*B+b)][3H] (incl bias).
// ---------------------------------------------------------------------------
__global__ __launch_bounds__(512, 2) void k_scan_x(
    const float* __restrict__ xg,
    const float* __restrict__ Whh,
    const float* __restrict__ bhh,
    float* __restrict__ y,
    int* __restrict__ barx,
    float* __restrict__ pool)
{
    __shared__ float wAll[12][HH];        // 48 KB
    __shared__ float stgL[32 * 256];      // 32 KB
    __shared__ float part[16][12][32];    // 24.6 KB
    __shared__ float bh[12];
    __shared__ double pool_l[128];

    const int tid = threadIdx.x;
    const int j0 = blockIdx.x * 4;

    for (int i = tid; i < 12 * 256; i += 512) {
        int r = i >> 8, c4 = (i & 255) * 4;
        int g = r >> 2, jj = r & 3;
        *(float4*)&wAll[r][c4] =
            *(const float4*)&Whh[(size_t)(g * HH + j0 + jj) * HH + c4];
    }
    if (tid < 12) bh[tid] = bhh[(tid >> 2) * HH + j0 + (tid & 3)];
    if (tid < 128) pool_l[tid] = 0.0;
    __syncthreads();

    const int gb = tid >> 2, gjj = tid & 3;
    float hp_reg = 0.f;
    for (int t = 0; t < TT; t++) {
        // prefetch this step's input gates before the barrier poll
        float xr = 0.f, xz = 0.f, xn = 0.f;
        if (tid < 128) {
            const float* xrow = xg + ((size_t)t * BB + gb) * G3;
            xr = xrow[j0 + gjj];
            xz = xrow[HH + j0 + gjj];
            xn = xrow[2 * HH + j0 + gjj];
        }
        if (t > 0) {
            if (tid < 8) {
                const int target = 32 * t;
                while (__hip_atomic_load(&barx[tid * 16], __ATOMIC_RELAXED,
                                         __HIP_MEMORY_SCOPE_AGENT) < target)
                    __builtin_amdgcn_s_sleep(2);
            }
            __syncthreads();
            mv_phase(wAll, stgL, part, y + (size_t)(t - 1) * BB * HH, 0, tid);
            __syncthreads();
        }
        if (tid < 128) {
            double hg0 = bh[gjj], hg1 = bh[4 + gjj], hg2 = bh[8 + gjj];
            if (t > 0) {
#pragma unroll
                for (int p = 0; p < 16; p++) {
                    hg0 += part[p][gjj][gb];
                    hg1 += part[p][4 + gjj][gb];
                    hg2 += part[p][8 + gjj][gb];
                }
            }
            float rr = 1.f / (1.f + expf(-(xr + (float)hg0)));
            float zz = 1.f / (1.f + expf(-(xz + (float)hg1)));
            float nn = tanhf(xn + rr * (float)hg2);
            float hnew = (1.f - zz) * nn + zz * hp_reg;
            hp_reg = hnew;
            __hip_atomic_store(&y[(size_t)t * BB * HH + gb * HH + j0 + gjj], hnew,
                               __ATOMIC_RELAXED, __HIP_MEMORY_SCOPE_AGENT);
            if (pool != nullptr) pool_l[tid] += (double)hnew;
        }
        if (t < TT - 1) {
            __syncthreads();
            if (tid == 0)
                __hip_atomic_fetch_add(&barx[(blockIdx.x & 7) * 16], 1,
                                       __ATOMIC_RELAXED, __HIP_MEMORY_SCOPE_AGENT);
        }
    }
    __syncthreads();
    if (pool != nullptr && tid < 128)
        pool[gb * HH + j0 + gjj] = (float)(pool_l[tid] * (1.0 / 512.0));
}

// ---------------------------------------------------------------------------
// xg GEMM: C[(t*B+b)][n] = sum_k A[(t*B+b)][k] * Bw[n][k] + bias[n]
// 128x128 tile, BK=16, 256 threads, 8x8 microtile. M=16384, N=3072, K=1024.
// ---------------------------------------------------------------------------
__global__ __launch_bounds__(256, 2) void k_gemm_xg(const float* __restrict__ A,
                                                    const float* __restrict__ Bw,
                                                    const float* __restrict__ bias,
                                                    float* __restrict__ C)
{
    __shared__ float As[16][132];
    __shared__ float Bs[16][132];
    const int tid = threadIdx.x;
    const int tx = tid & 15, ty = tid >> 4;
    const int bm = blockIdx.x * 128, bn = blockIdx.y * 128;
    float acc[8][8];
#pragma unroll
    for (int i = 0; i < 8; i++)
#pragma unroll
        for (int j = 0; j < 8; j++) acc[i][j] = 0.f;

    const int srow = tid >> 1, sch = (tid & 1) * 8;
    for (int k0 = 0; k0 < HH; k0 += 16) {
        {
            const float* ap = &A[(size_t)(bm + srow) * HH + k0 + sch];
            float4 v0 = *(const float4*)ap;
            float4 v1 = *(const float4*)(ap + 4);
            As[sch + 0][srow] = v0.x; As[sch + 1][srow] = v0.y;
            As[sch + 2][srow] = v0.z; As[sch + 3][srow] = v0.w;
            As[sch + 4][srow] = v1.x; As[sch + 5][srow] = v1.y;
            As[sch + 6][srow] = v1.z; As[sch + 7][srow] = v1.w;
            const float* bp = &Bw[(size_t)(bn + srow) * HH + k0 + sch];
            float4 u0 = *(const float4*)bp;
            float4 u1 = *(const float4*)(bp + 4);
            Bs[sch + 0][srow] = u0.x; Bs[sch + 1][srow] = u0.y;
            Bs[sch + 2][srow] = u0.z; Bs[sch + 3][srow] = u0.w;
            Bs[sch + 4][srow] = u1.x; Bs[sch + 5][srow] = u1.y;
            Bs[sch + 6][srow] = u1.z; Bs[sch + 7][srow] = u1.w;
        }
        __syncthreads();
#pragma unroll
        for (int k = 0; k < 16; k++) {
            float a[8], b[8];
            *(float4*)&a[0] = *(const float4*)&As[k][ty * 8];
            *(float4*)&a[4] = *(const float4*)&As[k][ty * 8 + 4];
            *(float4*)&b[0] = *(const float4*)&Bs[k][tx * 8];
            *(float4*)&b[4] = *(const float4*)&Bs[k][tx * 8 + 4];
#pragma unroll
            for (int i = 0; i < 8; i++)
#pragma unroll
                for (int j = 0; j < 8; j++)
                    acc[i][j] = fmaf(a[i], b[j], acc[i][j]);
        }
        __syncthreads();
    }
#pragma unroll
    for (int i = 0; i < 8; i++) {
        float o[8];
#pragma unroll
        for (int j = 0; j < 8; j++) o[j] = acc[i][j] + bias[bn + tx * 8 + j];
        float* cp = &C[(size_t)(bm + ty * 8 + i) * G3 + bn + tx * 8];
        *(float4*)cp = *(float4*)&o[0];
        *(float4*)(cp + 4) = *(float4*)&o[4];
    }
}

// ---------------------------------------------------------------------------
__global__ __launch_bounds__(256) void k_fc(const float* __restrict__ in,
                                            const float* __restrict__ w,
                                            const float* __restrict__ bias,
                                            float* __restrict__ out,
                                            int ind, int outd, int dorelu)
{
    int b = blockIdx.y;
    int o = blockIdx.x * 256 + threadIdx.x;
    if (o >= outd) return;
    const float* ip = in + (size_t)b * ind;
    const float* wp = w + (size_t)o * ind;
    double s = (double)bias[o];
    for (int k = 0; k < ind; k += 4) {
        float4 wv = *(const float4*)&wp[k];
        float4 iv = *(const float4*)&ip[k];
        s += (double)iv.x * wv.x + (double)iv.y * wv.y
           + (double)iv.z * wv.z + (double)iv.w * wv.w;
    }
    float v = (float)s;
    if (dorelu) v = fmaxf(v, 0.f);
    out[(size_t)b * outd + o] = v;
}

// ---------------------------------------------------------------------------
extern "C" void kernel_launch(void* const* d_in, const int* in_sizes, int n_in,
                              void* d_out, int out_size, void* d_ws, size_t ws_size,
                              hipStream_t stream)
{
    (void)in_sizes; (void)n_in; (void)out_size;
    const float* x    = (const float*)d_in[0];
    const float* Wih0 = (const float*)d_in[1];
    const float* Whh0 = (const float*)d_in[2];
    const float* bih0 = (const float*)d_in[3];
    const float* bhh0 = (const float*)d_in[4];
    const float* Wih1 = (const float*)d_in[5];
    const float* Whh1 = (const float*)d_in[6];
    const float* bih1 = (const float*)d_in[7];
    const float* bhh1 = (const float*)d_in[8];
    const float* Wih2 = (const float*)d_in[9];
    const float* Whh2 = (const float*)d_in[10];
    const float* bih2 = (const float*)d_in[11];
    const float* bhh2 = (const float*)d_in[12];
    const float* fc1w = (const float*)d_in[13];
    const float* fc1b = (const float*)d_in[14];
    const float* fc2w = (const float*)d_in[15];
    const float* fc2b = (const float*)d_in[16];
    const float* fc3w = (const float*)d_in[17];
    const float* fc3b = (const float*)d_in[18];

    int*   bars   = (int*)d_ws;
    float* pooled = (float*)d_ws + 512;
    float* fc1o   = pooled + 32 * 1024;
    float* fc2o   = fc1o + 32 * 512;
    float* y0     = fc2o + 32 * 256;                  // 67.1 MB
    float* y1     = y0 + (size_t)TT * BB * HH;        // 67.1 MB
    float* xg     = y1 + (size_t)TT * BB * HH;        // 201.3 MB (big path only)

    const size_t head  = (size_t)(512 + 32 * 1024 + 32 * 512 + 32 * 256) * 4;
    const size_t ybytes = (size_t)TT * BB * HH * 4;
    const size_t need_min  = head + 2 * ybytes;
    const size_t need_full = head + 2 * ybytes + (size_t)TT * BB * G3 * 4;
    if (ws_size < need_min) return;
    const bool big = (ws_size >= need_full);

    hipMemsetAsync(bars, 0, 3 * 128 * sizeof(int), stream);

    k_scan<8><<<256, 512, 0, stream>>>(x, Wih0, Whh0, bih0, bhh0, y0, bars, nullptr);

    if (big) {
        k_gemm_xg<<<dim3(128, 24), 256, 0, stream>>>(y0, Wih1, bih1, xg);
        k_scan_x<<<256, 512, 0, stream>>>(xg, Whh1, bhh1, y1, bars + 128, nullptr);
        k_gemm_xg<<<dim3(128, 24), 256, 0, stream>>>(y1, Wih2, bih2, xg);
        k_scan_x<<<256, 512, 0, stream>>>(xg, Whh2, bhh2, y0, bars + 256, pooled);
    } else {
        k_scan<HH><<<256, 512, 0, stream>>>(y0, Wih1, Whh1, bih1, bhh1, y1, bars + 128, nullptr);
        k_scan<HH><<<256, 512, 0, stream>>>(y1, Wih2, Whh2, bih2, bhh2, y0, bars + 256, pooled);
    }

    k_fc<<<dim3(2, 32), 256, 0, stream>>>(pooled, fc1w, fc1b, fc1o, HH, 512, 1);
    k_fc<<<dim3(1, 32), 256, 0, stream>>>(fc1o, fc2w, fc2b, fc2o, 512, 256, 1);
    k_fc<<<dim3(1, 32), 256, 0, stream>>>(fc2o, fc3w, fc3b, (float*)d_out, 256, 1, 0);
}

// Round 6
// 21282.178 us; speedup vs baseline: 2.0212x; 1.5698x over previous
//
#include <hip/hip_runtime.h>
#include <cmath>

#define TT 512
#define BB 32
#define HH 1024
#define G3 3072

// ---------------------------------------------------------------------------
// Shared matvec phase for the persistent scans. Lane tile: 12r x 4b x 4k.
// Stage LDS layout: [b][256] fp32, 16B-block index XOR-swizzled by (b&7).
// ---------------------------------------------------------------------------
__device__ __forceinline__ void mv_phase(
    float (*wAll)[HH],              // rows [wrow, wrow+12)
    float* stgL,                    // [32*256]
    float (*part)[12][32],          // [16][12][32]
    const float* __restrict__ src,  // [32][1024] row-major
    int wrow, int tid)
{
    const int wv = tid >> 6, l = tid & 63;
    const int ks = l >> 3, bg = l & 7;
    float acc[12][4];
#pragma unroll
    for (int r = 0; r < 12; r++) {
        acc[r][0] = 0.f; acc[r][1] = 0.f; acc[r][2] = 0.f; acc[r][3] = 0.f;
    }

    float4 ld[4];
#pragma unroll
    for (int i = 0; i < 4; i++)
        ld[i] = *(const float4*)&src[(size_t)(i * 8 + wv) * HH + l * 4];

    for (int c = 0; c < 4; c++) {
        __syncthreads();
#pragma unroll
        for (int i = 0; i < 4; i++) {
            int b = i * 8 + wv;
            *(float4*)&stgL[b * 256 + ((l ^ (b & 7)) << 2)] = ld[i];
        }
        __syncthreads();
        if (c < 3) {
#pragma unroll
            for (int i = 0; i < 4; i++)
                ld[i] = *(const float4*)&src[(size_t)(i * 8 + wv) * HH + (c + 1) * 256 + l * 4];
        }
        const int kw = c * 256 + wv * 32 + ks * 4;
        const int kb = wv * 8 + ks;
        float4 h4[4];
#pragma unroll
        for (int e = 0; e < 4; e++) {
            int b = bg * 4 + e;
            h4[e] = *(const float4*)&stgL[b * 256 + ((kb ^ (b & 7)) << 2)];
        }
#pragma unroll
        for (int r = 0; r < 12; r++) {
            float4 w4 = *(const float4*)&wAll[wrow + r][kw];
#pragma unroll
            for (int e = 0; e < 4; e++) {
                acc[r][e] = fmaf(w4.x, h4[e].x, acc[r][e]);
                acc[r][e] = fmaf(w4.y, h4[e].y, acc[r][e]);
                acc[r][e] = fmaf(w4.z, h4[e].z, acc[r][e]);
                acc[r][e] = fmaf(w4.w, h4[e].w, acc[r][e]);
            }
        }
    }
#pragma unroll
    for (int r = 0; r < 12; r++)
#pragma unroll
        for (int e = 0; e < 4; e++) {
            float v = acc[r][e];
            v += __shfl_xor(v, 16, 64);
            v += __shfl_xor(v, 32, 64);
            acc[r][e] = v;
        }
    if (l < 16) {
        int s = l >> 3, bgw = l & 7;
#pragma unroll
        for (int r = 0; r < 12; r++) {
            float4 o = make_float4(acc[r][0], acc[r][1], acc[r][2], acc[r][3]);
            *(float4*)&part[wv * 2 + s][r][bgw * 4] = o;
        }
    }
}

// ---------------------------------------------------------------------------
// Fallback / layer-0 scan (fused input phase; register-carried h_prev).
// ---------------------------------------------------------------------------
template<int IN_DIM>
__global__ __launch_bounds__(512, 2) void k_scan(
    const float* __restrict__ xsrc,   // IN_DIM==8: [B][T][8]; else [T][B][H]
    const float* __restrict__ Wih,
    const float* __restrict__ Whh,
    const float* __restrict__ bih,
    const float* __restrict__ bhh,
    float* __restrict__ y,
    int* __restrict__ barx,
    float* __restrict__ pool)
{
    __shared__ float wAll[24][HH];
    __shared__ float stgL[32 * 256];
    __shared__ float part[16][12][32];
    __shared__ float bi[12], bh[12];
    __shared__ double pool_l[128];

    const int tid = threadIdx.x;
    const int j0 = blockIdx.x * 4;

    for (int i = tid; i < 12 * 256; i += 512) {
        int r = i >> 8, c4 = (i & 255) * 4;
        int g = r >> 2, jj = r & 3;
        *(float4*)&wAll[r][c4] =
            *(const float4*)&Whh[(size_t)(g * HH + j0 + jj) * HH + c4];
    }
    if (IN_DIM == HH) {
        for (int i = tid; i < 12 * 256; i += 512) {
            int r = i >> 8, c4 = (i & 255) * 4;
            int g = r >> 2, jj = r & 3;
            *(float4*)&wAll[12 + r][c4] =
                *(const float4*)&Wih[(size_t)(g * HH + j0 + jj) * HH + c4];
        }
    } else {
        if (tid < 96) {
            int r = tid >> 3, d = tid & 7;
            int g = r >> 2, jj = r & 3;
            wAll[12 + r][d] = Wih[(size_t)(g * HH + j0 + jj) * IN_DIM + d];
        }
    }
    if (tid < 12) {
        int g = tid >> 2, jj = tid & 3;
        bi[tid] = bih[g * HH + j0 + jj];
        bh[tid] = bhh[g * HH + j0 + jj];
    }
    if (tid < 128) pool_l[tid] = 0.0;
    __syncthreads();

    float hp_reg = 0.f;
    for (int t = 0; t < TT; t++) {
        double ig0 = 0.0, ig1 = 0.0, ig2 = 0.0;
        if (IN_DIM == HH) {
            mv_phase(wAll, stgL, part, xsrc + (size_t)t * BB * HH, 12, tid);
            __syncthreads();
            if (tid < 128) {
                int b = tid >> 2, jj = tid & 3;
                ig0 = bi[jj]; ig1 = bi[4 + jj]; ig2 = bi[8 + jj];
#pragma unroll
                for (int p = 0; p < 16; p++) {
                    ig0 += part[p][jj][b];
                    ig1 += part[p][4 + jj][b];
                    ig2 += part[p][8 + jj][b];
                }
            }
        }
        if (t > 0) {
            if (tid < 8) {
                const int target = 32 * t;
                while (__hip_atomic_load(&barx[tid * 16], __ATOMIC_RELAXED,
                                         __HIP_MEMORY_SCOPE_AGENT) < target)
                    __builtin_amdgcn_s_sleep(2);
            }
            __syncthreads();
            mv_phase(wAll, stgL, part, y + (size_t)(t - 1) * BB * HH, 0, tid);
            __syncthreads();
        }
        if (tid < 128) {
            int b = tid >> 2, jj = tid & 3, jg = j0 + jj;
            double hg0 = bh[jj], hg1 = bh[4 + jj], hg2 = bh[8 + jj];
            if (t > 0) {
#pragma unroll
                for (int p = 0; p < 16; p++) {
                    hg0 += part[p][jj][b];
                    hg1 += part[p][4 + jj][b];
                    hg2 += part[p][8 + jj][b];
                }
            }
            if (IN_DIM != HH) {
                const float* xp = xsrc + ((size_t)b * TT + t) * IN_DIM;
                float xv[8];
                *(float4*)&xv[0] = *(const float4*)&xp[0];
                *(float4*)&xv[4] = *(const float4*)&xp[4];
                float s0 = 0.f, s1 = 0.f, s2 = 0.f;
#pragma unroll
                for (int d = 0; d < 8; d++) {
                    s0 = fmaf(wAll[12 + jj][d], xv[d], s0);
                    s1 = fmaf(wAll[16 + jj][d], xv[d], s1);
                    s2 = fmaf(wAll[20 + jj][d], xv[d], s2);
                }
                ig0 = (double)bi[jj] + s0;
                ig1 = (double)bi[4 + jj] + s1;
                ig2 = (double)bi[8 + jj] + s2;
            }
            float rr = 1.f / (1.f + expf(-(float)(ig0 + hg0)));
            float zz = 1.f / (1.f + expf(-(float)(ig1 + hg1)));
            float nn = tanhf((float)(ig2 + (double)rr * hg2));
            float hnew = (1.f - zz) * nn + zz * hp_reg;
            hp_reg = hnew;
            __hip_atomic_store(&y[(size_t)t * BB * HH + b * HH + jg], hnew,
                               __ATOMIC_RELAXED, __HIP_MEMORY_SCOPE_AGENT);
            if (pool != nullptr) pool_l[tid] += (double)hnew;
        }
        if (t < TT - 1) {
            __syncthreads();
            if (tid == 0)
                __hip_atomic_fetch_add(&barx[(blockIdx.x & 7) * 16], 1,
                                       __ATOMIC_RELAXED, __HIP_MEMORY_SCOPE_AGENT);
        }
    }
    __syncthreads();
    if (pool != nullptr && tid < 128) {
        int b = tid >> 2, jj = tid & 3;
        pool[b * HH + j0 + jj] = (float)(pool_l[tid] * (1.0 / 512.0));
    }
}

// ---------------------------------------------------------------------------
// Hidden-only CHUNKED scan over t in [t0,t1): input gates precomputed into
// xg[(t-t0)*B+b][3H] (incl bias). h carried via y across chunk kernels;
// pool accumulated into global double buffer (one owner thread per (b,j)).
// ---------------------------------------------------------------------------
__global__ __launch_bounds__(512, 2) void k_scan_x(
    const float* __restrict__ xg,
    const float* __restrict__ Whh,
    const float* __restrict__ bhh,
    float* __restrict__ y,
    int* __restrict__ barx,
    double* __restrict__ pool,
    int t0, int t1)
{
    __shared__ float wAll[12][HH];        // 48 KB
    __shared__ float stgL[32 * 256];      // 32 KB
    __shared__ float part[16][12][32];    // 24.6 KB
    __shared__ float bh[12];
    __shared__ double pool_l[128];

    const int tid = threadIdx.x;
    const int j0 = blockIdx.x * 4;

    for (int i = tid; i < 12 * 256; i += 512) {
        int r = i >> 8, c4 = (i & 255) * 4;
        int g = r >> 2, jj = r & 3;
        *(float4*)&wAll[r][c4] =
            *(const float4*)&Whh[(size_t)(g * HH + j0 + jj) * HH + c4];
    }
    if (tid < 12) bh[tid] = bhh[(tid >> 2) * HH + j0 + (tid & 3)];
    if (tid < 128) pool_l[tid] = 0.0;

    const int gb = tid >> 2, gjj = tid & 3;
    float hp_reg = 0.f;
    if (t0 > 0 && tid < 128)
        hp_reg = y[(size_t)(t0 - 1) * BB * HH + gb * HH + j0 + gjj];
    __syncthreads();

    for (int t = t0; t < t1; t++) {
        // prefetch this step's input gates before the barrier poll
        float xr = 0.f, xz = 0.f, xn = 0.f;
        if (tid < 128) {
            const float* xrow = xg + ((size_t)(t - t0) * BB + gb) * G3;
            xr = xrow[j0 + gjj];
            xz = xrow[HH + j0 + gjj];
            xn = xrow[2 * HH + j0 + gjj];
        }
        if (t > t0) {
            if (tid < 8) {
                const int target = 32 * (t - t0);
                while (__hip_atomic_load(&barx[tid * 16], __ATOMIC_RELAXED,
                                         __HIP_MEMORY_SCOPE_AGENT) < target)
                    __builtin_amdgcn_s_sleep(2);
            }
            __syncthreads();
        }
        if (t > 0) {   // t==t0>0: h from previous chunk kernel, no wait needed
            mv_phase(wAll, stgL, part, y + (size_t)(t - 1) * BB * HH, 0, tid);
            __syncthreads();
        }
        if (tid < 128) {
            double hg0 = bh[gjj], hg1 = bh[4 + gjj], hg2 = bh[8 + gjj];
            if (t > 0) {
#pragma unroll
                for (int p = 0; p < 16; p++) {
                    hg0 += part[p][gjj][gb];
                    hg1 += part[p][4 + gjj][gb];
                    hg2 += part[p][8 + gjj][gb];
                }
            }
            float rr = 1.f / (1.f + expf(-(xr + (float)hg0)));
            float zz = 1.f / (1.f + expf(-(xz + (float)hg1)));
            float nn = tanhf(xn + rr * (float)hg2);
            float hnew = (1.f - zz) * nn + zz * hp_reg;
            hp_reg = hnew;
            __hip_atomic_store(&y[(size_t)t * BB * HH + gb * HH + j0 + gjj], hnew,
                               __ATOMIC_RELAXED, __HIP_MEMORY_SCOPE_AGENT);
            if (pool != nullptr) pool_l[tid] += (double)hnew;
        }
        if (t < t1 - 1) {
            __syncthreads();
            if (tid == 0)
                __hip_atomic_fetch_add(&barx[(blockIdx.x & 7) * 16], 1,
                                       __ATOMIC_RELAXED, __HIP_MEMORY_SCOPE_AGENT);
        }
    }
    __syncthreads();
    if (pool != nullptr && tid < 128)
        pool[gb * HH + j0 + gjj] += pool_l[tid];   // serialized chunk kernels
}

// ---------------------------------------------------------------------------
// pooled_f[i] = pooled_d[i] / 512
// ---------------------------------------------------------------------------
__global__ __launch_bounds__(512) void k_poolfin(const double* __restrict__ pd,
                                                 float* __restrict__ pf)
{
    int i = blockIdx.x * 512 + threadIdx.x;
    if (i < BB * HH) pf[i] = (float)(pd[i] * (1.0 / 512.0));
}

// ---------------------------------------------------------------------------
// xg GEMM: C[m][n] = sum_k A[m][k] * Bw[n][k] + bias[n]
// 128x128 tile, BK=16, 256 threads, 8x8 microtile.
// ---------------------------------------------------------------------------
__global__ __launch_bounds__(256, 2) void k_gemm_xg(const float* __restrict__ A,
                                                    const float* __restrict__ Bw,
                                                    const float* __restrict__ bias,
                                                    float* __restrict__ C)
{
    __shared__ float As[16][132];
    __shared__ float Bs[16][132];
    const int tid = threadIdx.x;
    const int tx = tid & 15, ty = tid >> 4;
    const int bm = blockIdx.x * 128, bn = blockIdx.y * 128;
    float acc[8][8];
#pragma unroll
    for (int i = 0; i < 8; i++)
#pragma unroll
        for (int j = 0; j < 8; j++) acc[i][j] = 0.f;

    const int srow = tid >> 1, sch = (tid & 1) * 8;
    for (int k0 = 0; k0 < HH; k0 += 16) {
        {
            const float* ap = &A[(size_t)(bm + srow) * HH + k0 + sch];
            float4 v0 = *(const float4*)ap;
            float4 v1 = *(const float4*)(ap + 4);
            As[sch + 0][srow] = v0.x; As[sch + 1][srow] = v0.y;
            As[sch + 2][srow] = v0.z; As[sch + 3][srow] = v0.w;
            As[sch + 4][srow] = v1.x; As[sch + 5][srow] = v1.y;
            As[sch + 6][srow] = v1.z; As[sch + 7][srow] = v1.w;
            const float* bp = &Bw[(size_t)(bn + srow) * HH + k0 + sch];
            float4 u0 = *(const float4*)bp;
            float4 u1 = *(const float4*)(bp + 4);
            Bs[sch + 0][srow] = u0.x; Bs[sch + 1][srow] = u0.y;
            Bs[sch + 2][srow] = u0.z; Bs[sch + 3][srow] = u0.w;
            Bs[sch + 4][srow] = u1.x; Bs[sch + 5][srow] = u1.y;
            Bs[sch + 6][srow] = u1.z; Bs[sch + 7][srow] = u1.w;
        }
        __syncthreads();
#pragma unroll
        for (int k = 0; k < 16; k++) {
            float a[8], b[8];
            *(float4*)&a[0] = *(const float4*)&As[k][ty * 8];
            *(float4*)&a[4] = *(const float4*)&As[k][ty * 8 + 4];
            *(float4*)&b[0] = *(const float4*)&Bs[k][tx * 8];
            *(float4*)&b[4] = *(const float4*)&Bs[k][tx * 8 + 4];
#pragma unroll
            for (int i = 0; i < 8; i++)
#pragma unroll
                for (int j = 0; j < 8; j++)
                    acc[i][j] = fmaf(a[i], b[j], acc[i][j]);
        }
        __syncthreads();
    }
#pragma unroll
    for (int i = 0; i < 8; i++) {
        float o[8];
#pragma unroll
        for (int j = 0; j < 8; j++) o[j] = acc[i][j] + bias[bn + tx * 8 + j];
        float* cp = &C[(size_t)(bm + ty * 8 + i) * G3 + bn + tx * 8];
        *(float4*)cp = *(float4*)&o[0];
        *(float4*)(cp + 4) = *(float4*)&o[4];
    }
}

// ---------------------------------------------------------------------------
__global__ __launch_bounds__(256) void k_fc(const float* __restrict__ in,
                                            const float* __restrict__ w,
                                            const float* __restrict__ bias,
                                            float* __restrict__ out,
                                            int ind, int outd, int dorelu)
{
    int b = blockIdx.y;
    int o = blockIdx.x * 256 + threadIdx.x;
    if (o >= outd) return;
    const float* ip = in + (size_t)b * ind;
    const float* wp = w + (size_t)o * ind;
    double s = (double)bias[o];
    for (int k = 0; k < ind; k += 4) {
        float4 wv = *(const float4*)&wp[k];
        float4 iv = *(const float4*)&ip[k];
        s += (double)iv.x * wv.x + (double)iv.y * wv.y
           + (double)iv.z * wv.z + (double)iv.w * wv.w;
    }
    float v = (float)s;
    if (dorelu) v = fmaxf(v, 0.f);
    out[(size_t)b * outd + o] = v;
}

// ---------------------------------------------------------------------------
extern "C" void kernel_launch(void* const* d_in, const int* in_sizes, int n_in,
                              void* d_out, int out_size, void* d_ws, size_t ws_size,
                              hipStream_t stream)
{
    (void)in_sizes; (void)n_in; (void)out_size;
    const float* x    = (const float*)d_in[0];
    const float* Wih[3] = {(const float*)d_in[1], (const float*)d_in[5], (const float*)d_in[9]};
    const float* Whh[3] = {(const float*)d_in[2], (const float*)d_in[6], (const float*)d_in[10]};
    const float* bih[3] = {(const float*)d_in[3], (const float*)d_in[7], (const float*)d_in[11]};
    const float* bhh[3] = {(const float*)d_in[4], (const float*)d_in[8], (const float*)d_in[12]};
    const float* fc1w = (const float*)d_in[13];
    const float* fc1b = (const float*)d_in[14];
    const float* fc2w = (const float*)d_in[15];
    const float* fc2b = (const float*)d_in[16];
    const float* fc3w = (const float*)d_in[17];
    const float* fc3b = (const float*)d_in[18];

    // workspace layout
    int*    bars     = (int*)d_ws;                          // 96 groups x 128 ints = 48 KB
    double* pooled_d = (double*)((char*)d_ws + 96 * 128 * 4);  // 256 KB
    float*  pooled_f = (float*)(pooled_d + BB * HH);        // 128 KB
    float*  fc1o     = pooled_f + BB * HH;
    float*  fc2o     = fc1o + BB * 512;
    float*  y0       = fc2o + BB * 256;                     // 67.1 MB
    float*  y1       = y0 + (size_t)TT * BB * HH;           // 67.1 MB
    float*  xg       = y1 + (size_t)TT * BB * HH;           // CH*393 KB

    const size_t base = (size_t)((char*)xg - (char*)d_ws);
    if (ws_size < base) return;  // not even the fallback fits

    int CH = 0;   // timestep chunk for xg precompute; 0 = fallback path
    for (int c = 512; c >= 16; c >>= 1) {
        if (base + (size_t)c * BB * G3 * 4 <= ws_size) { CH = c; break; }
    }

    hipMemsetAsync(bars, 0, 96 * 128 * sizeof(int), stream);
    hipMemsetAsync(pooled_d, 0, BB * HH * sizeof(double), stream);

    int binst = 0;
    // layer 0 (IN=8) always full-scan
    k_scan<8><<<256, 512, 0, stream>>>(x, Wih[0], Whh[0], bih[0], bhh[0], y0,
                                       bars + (binst++) * 128, nullptr);

    if (CH > 0) {
        float* ybuf[2] = {y0, y1};
        for (int l = 1; l <= 2; l++) {
            const float* src = ybuf[(l - 1) & 1];
            float* dst = ybuf[l & 1];   // layer 2 reuses y0
            double* pl = (l == 2) ? pooled_d : nullptr;
            for (int t0 = 0; t0 < TT; t0 += CH) {
                int t1 = t0 + CH;
                k_gemm_xg<<<dim3(CH * BB / 128, G3 / 128), 256, 0, stream>>>(
                    src + (size_t)t0 * BB * HH, Wih[l], bih[l], xg);
                k_scan_x<<<256, 512, 0, stream>>>(
                    xg, Whh[l], bhh[l], dst, bars + (binst++) * 128, pl, t0, t1);
            }
        }
        k_poolfin<<<(BB * HH + 511) / 512, 512, 0, stream>>>(pooled_d, pooled_f);
    } else {
        k_scan<HH><<<256, 512, 0, stream>>>(y0, Wih[1], Whh[1], bih[1], bhh[1], y1,
                                            bars + (binst++) * 128, nullptr);
        k_scan<HH><<<256, 512, 0, stream>>>(y1, Wih[2], Whh[2], bih[2], bhh[2], y0,
                                            bars + (binst++) * 128, pooled_f);
    }

    k_fc<<<dim3(2, 32), 256, 0, stream>>>(pooled_f, fc1w, fc1b, fc1o, HH, 512, 1);
    k_fc<<<dim3(1, 32), 256, 0, stream>>>(fc1o, fc2w, fc2b, fc2o, 512, 256, 1);
    k_fc<<<dim3(1, 32), 256, 0, stream>>>(fc2o, fc3w, fc3b, (float*)d_out, 256, 1, 0);
}